// Round 12
// baseline (120.798 us; speedup 1.0000x reference)
//
#include <hip/hip_runtime.h>

#define B_ 32
#define L_ 1024
#define D_ 128
#define NT 512

typedef __attribute__((ext_vector_type(8))) short bf8_t;
typedef __attribute__((ext_vector_type(4))) float f4_t;

__device__ __forceinline__ unsigned cvtpk(float lo, float hi) {
  unsigned r;
  asm("v_cvt_pk_bf16_f32 %0, %1, %2" : "=v"(r) : "v"(lo), "v"(hi));
  return r;
}

__device__ __forceinline__ void gload16(const void* g, void* l) {
  __builtin_amdgcn_global_load_lds((const __attribute__((address_space(1))) void*)g,
                                   (__attribute__((address_space(3))) void*)l, 16, 0, 0);
}

// Prologue: pre-swizzled bf16 X panels + sq + channel-0 copy + W packed as
// half-K-padded 16x16x32 B-fragments:
//   Wt element idx = which*262144 + ((jt*2+wc)*8 + m)*512 + lane*8 + e
//   value (e<4): bf16( W[(jt*32 + wc*16 + (lane>>4)*4 + e)*128 + m*16 + (lane&15)] )
//   value (e>=4): 0   (pairs with A-fragment zero slots)
__global__ __launch_bounds__(256)
void prep_kernel(const float* __restrict__ x0, const float* __restrict__ x1,
                 const float* __restrict__ W0, const float* __restrict__ W1,
                 short* __restrict__ Xs, float* __restrict__ sq,
                 short* __restrict__ Wt, float* __restrict__ out) {
  int bid = blockIdx.x;
  if (bid < 8192) {
    int t = bid * 256 + threadIdx.x;     // 0 .. 2097151
    int row_id = t >> 5;                 // (which,b,row)
    int qp = t & 31;
    int which = row_id >> 15;
    int b = (row_id >> 10) & 31;
    int row = row_id & 1023;
    const float* x = which ? x1 : x0;
    float4 v = *(const float4*)(x + ((size_t)b * L_ + row) * D_ + qp * 4);
    float* o = out + (size_t)which * (B_ * 2 * L_ * D_) + (size_t)b * (2 * L_ * D_)
             + (size_t)row * D_ + qp * 4;
    *(float4*)o = v;
    unsigned w0 = cvtpk(v.x, v.y), w1 = cvtpk(v.z, v.w);
    char* xb = (char*)Xs + (size_t)row_id * 256 + ((qp * 8) ^ ((row & 7) << 4));
    *(uint2*)xb = make_uint2(w0, w1);
    float s = v.x * v.x + v.y * v.y + v.z * v.z + v.w * v.w;
    s += __shfl_xor(s, 1); s += __shfl_xor(s, 2); s += __shfl_xor(s, 4);
    s += __shfl_xor(s, 8); s += __shfl_xor(s, 16);
    if (qp == 0) sq[row_id] = s;
  } else {
    int idx = (bid - 8192) * 256 + threadIdx.x;  // 0..524287
    int which = idx >> 18;
    int rm = idx & 262143;
    int frag = rm >> 9;         // (jt*2+wc)*8 + m
    int s9 = rm & 511;
    int lane = s9 >> 3;
    int e = s9 & 7;
    int m = frag & 7;
    int wc = (frag >> 3) & 1;
    int jt = frag >> 4;
    short val = 0;
    if (e < 4) {
      const float* W = which ? W1 : W0;
      int j = jt * 32 + wc * 16 + (lane >> 4) * 4 + e;
      int d = m * 16 + (lane & 15);
      float wv = W[j * D_ + d];
      val = (short)(cvtpk(wv, wv) & 0xffffu);
    }
    Wt[idx] = val;
  }
}

__global__ __launch_bounds__(NT, 4)
void fused_attnconv(const short* __restrict__ Xs, const float* __restrict__ sq,
                    const short* __restrict__ Wt, float* __restrict__ out) {
  // LDS: [0,8K) y0 [8K,16K) y1 [32K,36K) sqy ; epilogue reuses [0,32K) as ex
  __shared__ char smem[36864];
  float* sqyL = (float*)(smem + 32768);

  const int bid = blockIdx.x;
  const int x = bid & 7, g = bid >> 3;
  const int p = x + 8 * (g >> 4);       // panel id = which*32+b
  const int it = g & 15;                // i-tile (64 rows)
  const int which = p >> 5, b = p & 31;
  const int i0 = it * 64;
  const int po = (which ^ 1) * 32 + b;  // opposite tensor: y-side

  const char* apanel = (const char*)Xs + (size_t)p * (L_ * 256);
  const char* ypanel = (const char*)Xs + (size_t)po * (L_ * 256);
  const float* sqx_p = sq + p * L_;
  const float* sqy_p = sq + po * L_;
  float* Oc1 = out + (size_t)which * (B_ * 2 * L_ * D_) + (size_t)b * (2 * L_ * D_) + (L_ * D_);

  const int tid = threadIdx.x;
  const int lane = tid & 63;
  const int w = tid >> 6;
  const int l15 = lane & 15;
  const int q = lane >> 4;
  const int wr = w & 3;           // i-strip: rows I0..I0+15
  const int wc = w >> 2;          // j-quadrant within 32-wide tile (K-split)
  const int I0 = wr * 16;
  const int JS = wc * 16;
  const int swz = (l15 & 7) << 4;

  // a-fragments in registers (global Xs is pre-swizzled -> apply same XOR)
  bf8_t afr[4];
#pragma unroll
  for (int kb = 0; kb < 4; ++kb)
    afr[kb] = *(const bf8_t*)(apanel + (size_t)(i0 + I0 + l15) * 256 + ((kb * 64 + q * 16) ^ swz));
  const float sxv = sqx_p[i0 + I0 + l15];

  // stage sqy (4 KB, once) + y-tile 0 (8 KB)
  if (tid < 256) {
    *(f4_t*)(sqyL + tid * 4) = *(const f4_t*)(sqy_p + tid * 4);
  }
  gload16(ypanel + tid * 16, smem + tid * 16);

  f4_t z4 = {0.f, 0.f, 0.f, 0.f};
  f4_t acc[8];
#pragma unroll
  for (int m = 0; m < 8; ++m) acc[m] = z4;

  __syncthreads();  // vmcnt+lgkm drained: tile 0 + sqy staged

  for (int jt = 0; jt < 32; ++jt) {
    const int cur = jt & 1;
    char* yB = smem + cur * 8192;

    // 1) prefetch next y-tile (8 KB)
    if (jt < 31)
      gload16(ypanel + (jt + 1) * 8192 + tid * 16, smem + (1 - cur) * 8192 + tid * 16);

    // 2) W B-fragments -> regs (8 x contiguous 1KB, L1/L2-hot)
    const short* Wb = Wt + which * 262144 + ((jt * 2 + wc) * 8) * 512 + lane * 8;
    bf8_t wf[8];
#pragma unroll
    for (int m = 0; m < 8; ++m)
      wf[m] = *(const bf8_t*)(Wb + m * 512);

    // 3) sy for this wave's j-quadrant
    f4_t sy = *(const f4_t*)(sqyL + jt * 32 + JS + q * 4);

    // 4) MFMA-1 (swapped): ST = y . a^T over (i = I0+l15, j = jt*32+JS+q*4+r)
    f4_t ST = z4;
#pragma unroll
    for (int kb = 0; kb < 4; ++kb) {
      const int kc = (kb * 64 + q * 16) ^ swz;
      bf8_t yf = *(const bf8_t*)(yB + (JS + l15) * 256 + kc);
      ST = __builtin_amdgcn_mfma_f32_16x16x32_bf16(yf, afr[kb], ST, 0, 0, 0);
    }

    // 5) elementwise A = 1/(1+dist) -> A-fragment IN REGISTERS (half-K-padded)
    float A0 = __builtin_amdgcn_rcpf(1.0f + __builtin_amdgcn_sqrtf(fmaxf(__builtin_fmaf(-2.f, ST[0], sxv + sy[0]), 0.f)));
    float A1 = __builtin_amdgcn_rcpf(1.0f + __builtin_amdgcn_sqrtf(fmaxf(__builtin_fmaf(-2.f, ST[1], sxv + sy[1]), 0.f)));
    float A2 = __builtin_amdgcn_rcpf(1.0f + __builtin_amdgcn_sqrtf(fmaxf(__builtin_fmaf(-2.f, ST[2], sxv + sy[2]), 0.f)));
    float A3 = __builtin_amdgcn_rcpf(1.0f + __builtin_amdgcn_sqrtf(fmaxf(__builtin_fmaf(-2.f, ST[3], sxv + sy[3]), 0.f)));
    union { int4 i4; bf8_t s8; } pu;
    pu.i4 = make_int4((int)cvtpk(A0, A1), (int)cvtpk(A2, A3), 0, 0);
    bf8_t pf = pu.s8;

    // 6) MFMA-2 (K=32 intrinsic, half-utilized; zero slots pair with zero W):
    //    acc[m] += P[:, wave's 16 j] . W[16 j, d-block m]
#pragma unroll
    for (int m = 0; m < 8; ++m)
      acc[m] = __builtin_amdgcn_mfma_f32_16x16x32_bf16(pf, wf[m], acc[m], 0, 0, 0);

    __syncthreads();  // single barrier: next y staged + all waves done with yB
  }

  // epilogue: pair-reduce partial-j accs across wc partners (R7-verified), store
  f4_t* ex = (f4_t*)smem;
  const int partner = w ^ 4;
#pragma unroll
  for (int k = 0; k < 4; ++k)
    ex[w * 256 + k * 64 + lane] = acc[(1 - wc) * 4 + k];  // send partner's d-range
  __syncthreads();
#pragma unroll
  for (int k = 0; k < 4; ++k) {
    const int m = wc * 4 + k;
    f4_t other = ex[partner * 256 + k * 64 + lane];
    const int d = m * 16 + l15;
#pragma unroll
    for (int r = 0; r < 4; ++r)
      Oc1[(size_t)(i0 + I0 + q * 4 + r) * D_ + d] = acc[m][r] + other[r];
  }
}

extern "C" void kernel_launch(void* const* d_in, const int* in_sizes, int n_in,
                              void* d_out, int out_size, void* d_ws, size_t ws_size,
                              hipStream_t stream) {
  const float* x0 = (const float*)d_in[0];
  const float* x1 = (const float*)d_in[1];
  const float* W0 = (const float*)d_in[2];
  const float* W1 = (const float*)d_in[3];
  float* out = (float*)d_out;

  char* ws = (char*)d_ws;
  short* Wt = (short*)ws;                        // 1 MB, half-K-padded B-fragments
  short* Xs = (short*)(ws + 1048576);            // 16.78 MB, pre-swizzled bf16
  float* sq = (float*)(ws + 1048576 + 16777216); // 256 KB

  prep_kernel<<<10240, 256, 0, stream>>>(x0, x1, W0, W1, Xs, sq, Wt, out);
  fused_attnconv<<<1024, NT, 0, stream>>>(Xs, sq, Wt, out);
}

// Round 13
// 89.860 us; speedup vs baseline: 1.3443x; 1.3443x over previous
//
#include <hip/hip_runtime.h>

#define B_ 32
#define L_ 1024
#define D_ 128
#define NT 512

typedef __attribute__((ext_vector_type(8))) short bf8_t;
typedef __attribute__((ext_vector_type(4))) float f4_t;

__device__ __forceinline__ unsigned cvtpk(float lo, float hi) {
  unsigned r;
  asm("v_cvt_pk_bf16_f32 %0, %1, %2" : "=v"(r) : "v"(lo), "v"(hi));
  return r;
}

__device__ __forceinline__ void gload16(const void* g, void* l) {
  __builtin_amdgcn_global_load_lds((const __attribute__((address_space(1))) void*)g,
                                   (__attribute__((address_space(3))) void*)l, 16, 0, 0);
}

// Prologue (R10-verified): pre-swizzled bf16 X panels + sq + channel-0 copy +
// W in fragment-coalesced layout Wc[which][j/32][d][j%32] (bf16).
__global__ __launch_bounds__(256)
void prep_kernel(const float* __restrict__ x0, const float* __restrict__ x1,
                 const float* __restrict__ W0, const float* __restrict__ W1,
                 short* __restrict__ Xs, float* __restrict__ sq,
                 short* __restrict__ Wt, float* __restrict__ out) {
  int bid = blockIdx.x;
  if (bid < 8192) {
    int t = bid * 256 + threadIdx.x;     // 0 .. 2097151
    int row_id = t >> 5;                 // (which,b,row)
    int qp = t & 31;
    int which = row_id >> 15;
    int b = (row_id >> 10) & 31;
    int row = row_id & 1023;
    const float* x = which ? x1 : x0;
    float4 v = *(const float4*)(x + ((size_t)b * L_ + row) * D_ + qp * 4);
    float* o = out + (size_t)which * (B_ * 2 * L_ * D_) + (size_t)b * (2 * L_ * D_)
             + (size_t)row * D_ + qp * 4;
    *(float4*)o = v;
    unsigned w0 = cvtpk(v.x, v.y), w1 = cvtpk(v.z, v.w);
    char* xb = (char*)Xs + (size_t)row_id * 256 + ((qp * 8) ^ ((row & 7) << 4));
    *(uint2*)xb = make_uint2(w0, w1);
    float s = v.x * v.x + v.y * v.y + v.z * v.z + v.w * v.w;
    s += __shfl_xor(s, 1); s += __shfl_xor(s, 2); s += __shfl_xor(s, 4);
    s += __shfl_xor(s, 8); s += __shfl_xor(s, 16);
    if (qp == 0) sq[row_id] = s;
  } else {
    int idx = (bid - 8192) * 256 + threadIdx.x;  // 0..262143
    int which = idx >> 17;
    int rm = idx & 131071;
    int j32 = rm >> 12;       // 32 tiles of 32 j
    int d = (rm >> 5) & 127;
    int jj = rm & 31;
    const float* W = which ? W1 : W0;
    float wv = W[(j32 * 32 + jj) * D_ + d];
    Wt[idx] = (short)(cvtpk(wv, wv) & 0xffffu);
  }
}

__global__ __launch_bounds__(NT, 4)
void fused_attnconv(const short* __restrict__ Xs, const float* __restrict__ sq,
                    const short* __restrict__ Wt, float* __restrict__ out) {
  // LDS: [0,8K) y0 [8K,16K) y1 [16K,24K) P0 [24K,32K) P1 [32K,36K) sqy
  __shared__ char smem[36864];
  char* Pb0 = smem + 16384;
  char* Pb1 = smem + 24576;
  float* sqyL = (float*)(smem + 32768);

  const int bid = blockIdx.x;
  const int x = bid & 7, g = bid >> 3;
  const int p = x + 8 * (g >> 4);       // panel id = which*32+b
  const int it = g & 15;                // i-tile (64 rows)
  const int which = p >> 5, b = p & 31;
  const int i0 = it * 64;
  const int po = (which ^ 1) * 32 + b;  // opposite tensor: y-side

  const char* apanel = (const char*)Xs + (size_t)p * (L_ * 256);
  const char* ypanel = (const char*)Xs + (size_t)po * (L_ * 256);
  const float* sqx_p = sq + p * L_;
  const float* sqy_p = sq + po * L_;
  float* Oc1 = out + (size_t)which * (B_ * 2 * L_ * D_) + (size_t)b * (2 * L_ * D_) + (L_ * D_);

  const int tid = threadIdx.x;
  const int lane = tid & 63;
  const int w = tid >> 6;
  const int l15 = lane & 15;
  const int q = lane >> 4;
  const int wr = w & 3;           // i-strip: rows I0..I0+15
  const int wc = w >> 2;          // MFMA-1: j-quadrant; MFMA-2: d-half
  const int I0 = wr * 16;
  const int JS = wc * 16;         // j-offset within 32-wide tile
  const int D0 = wc * 64;         // d-half for output
  const int swz = (l15 & 7) << 4;

  // ---- hoisted, loop-invariant offsets (bytes) ----
  const int yo0 = (JS + l15) * 256 + ((0 * 64 + q * 16) ^ swz);
  const int yo1 = (JS + l15) * 256 + ((1 * 64 + q * 16) ^ swz);
  const int yo2 = (JS + l15) * 256 + ((2 * 64 + q * 16) ^ swz);
  const int yo3 = (JS + l15) * 256 + ((3 * 64 + q * 16) ^ swz);
  const int pwo = (I0 + l15) * 128 + ((JS * 2 + q * 8) ^ swz);
  const int pro = (I0 + l15) * 128 + ((q * 16) ^ swz);

  // a-fragments in registers (global Xs is pre-swizzled -> apply same XOR)
  bf8_t afr[4];
#pragma unroll
  for (int kb = 0; kb < 4; ++kb)
    afr[kb] = *(const bf8_t*)(apanel + (size_t)(i0 + I0 + l15) * 256 + ((kb * 64 + q * 16) ^ swz));
  const float sxv = sqx_p[i0 + I0 + l15];

  // running pointers
  const short* wptr = Wt + which * 131072 + (D0 + l15) * 32 + q * 8;  // += 4096/iter
  const char* ypref = ypanel + 8192 + (size_t)tid * 16;               // src of tile jt+1
  char* ydst0 = smem + 8192 + tid * 16;  // prefetch dst while computing buf0
  char* ydst1 = smem + tid * 16;         // prefetch dst while computing buf1
  const float* syp = sqyL + JS + q * 4;  // += 32/iter

  // stage sqy (4 KB, once) + y-tile 0 (8 KB)
  if (tid < 256) {
    *(f4_t*)(sqyL + tid * 4) = *(const f4_t*)(sqy_p + tid * 4);
  }
  gload16(ypanel + (size_t)tid * 16, smem + tid * 16);

  f4_t z4 = {0.f, 0.f, 0.f, 0.f};
  f4_t acc[4] = {z4, z4, z4, z4};

  __syncthreads();  // vmcnt+lgkm drained: tile 0 + sqy staged

#pragma unroll 1
  for (int pr = 0; pr < 16; ++pr) {
    // ================= half A: jt = 2*pr, compute buf0, prefetch -> buf1 ====
    {
      bf8_t wf0 = *(const bf8_t*)(wptr);
      bf8_t wf1 = *(const bf8_t*)(wptr + 512);
      bf8_t wf2 = *(const bf8_t*)(wptr + 1024);
      bf8_t wf3 = *(const bf8_t*)(wptr + 1536);
      wptr += 4096;
      gload16(ypref, ydst0);  // tile 2*pr+1 (always exists)
      ypref += 8192;
      f4_t sy = *(const f4_t*)syp;
      syp += 32;

      f4_t ST = z4;
      bf8_t ya = *(const bf8_t*)(smem + yo0);
      ST = __builtin_amdgcn_mfma_f32_16x16x32_bf16(ya, afr[0], ST, 0, 0, 0);
      ya = *(const bf8_t*)(smem + yo1);
      ST = __builtin_amdgcn_mfma_f32_16x16x32_bf16(ya, afr[1], ST, 0, 0, 0);
      ya = *(const bf8_t*)(smem + yo2);
      ST = __builtin_amdgcn_mfma_f32_16x16x32_bf16(ya, afr[2], ST, 0, 0, 0);
      ya = *(const bf8_t*)(smem + yo3);
      ST = __builtin_amdgcn_mfma_f32_16x16x32_bf16(ya, afr[3], ST, 0, 0, 0);

      float A0 = __builtin_amdgcn_rcpf(1.0f + __builtin_amdgcn_sqrtf(fmaxf(__builtin_fmaf(-2.f, ST[0], sxv + sy[0]), 0.f)));
      float A1 = __builtin_amdgcn_rcpf(1.0f + __builtin_amdgcn_sqrtf(fmaxf(__builtin_fmaf(-2.f, ST[1], sxv + sy[1]), 0.f)));
      float A2 = __builtin_amdgcn_rcpf(1.0f + __builtin_amdgcn_sqrtf(fmaxf(__builtin_fmaf(-2.f, ST[2], sxv + sy[2]), 0.f)));
      float A3 = __builtin_amdgcn_rcpf(1.0f + __builtin_amdgcn_sqrtf(fmaxf(__builtin_fmaf(-2.f, ST[3], sxv + sy[3]), 0.f)));
      *(uint2*)(Pb0 + pwo) = make_uint2(cvtpk(A0, A1), cvtpk(A2, A3));

      __syncthreads();  // P0 complete block-wide; tile 2*pr+1 staged in buf1

      bf8_t pf = *(const bf8_t*)(Pb0 + pro);
      acc[0] = __builtin_amdgcn_mfma_f32_16x16x32_bf16(pf, wf0, acc[0], 0, 0, 0);
      acc[1] = __builtin_amdgcn_mfma_f32_16x16x32_bf16(pf, wf1, acc[1], 0, 0, 0);
      acc[2] = __builtin_amdgcn_mfma_f32_16x16x32_bf16(pf, wf2, acc[2], 0, 0, 0);
      acc[3] = __builtin_amdgcn_mfma_f32_16x16x32_bf16(pf, wf3, acc[3], 0, 0, 0);
    }
    // ================= half B: jt = 2*pr+1, compute buf1, prefetch -> buf0 ==
    {
      bf8_t wf0 = *(const bf8_t*)(wptr);
      bf8_t wf1 = *(const bf8_t*)(wptr + 512);
      bf8_t wf2 = *(const bf8_t*)(wptr + 1024);
      bf8_t wf3 = *(const bf8_t*)(wptr + 1536);
      wptr += 4096;
      if (pr != 15) gload16(ypref, ydst1);  // tile 2*pr+2
      ypref += 8192;
      f4_t sy = *(const f4_t*)syp;
      syp += 32;

      f4_t ST = z4;
      bf8_t ya = *(const bf8_t*)(smem + 8192 + yo0);
      ST = __builtin_amdgcn_mfma_f32_16x16x32_bf16(ya, afr[0], ST, 0, 0, 0);
      ya = *(const bf8_t*)(smem + 8192 + yo1);
      ST = __builtin_amdgcn_mfma_f32_16x16x32_bf16(ya, afr[1], ST, 0, 0, 0);
      ya = *(const bf8_t*)(smem + 8192 + yo2);
      ST = __builtin_amdgcn_mfma_f32_16x16x32_bf16(ya, afr[2], ST, 0, 0, 0);
      ya = *(const bf8_t*)(smem + 8192 + yo3);
      ST = __builtin_amdgcn_mfma_f32_16x16x32_bf16(ya, afr[3], ST, 0, 0, 0);

      float A0 = __builtin_amdgcn_rcpf(1.0f + __builtin_amdgcn_sqrtf(fmaxf(__builtin_fmaf(-2.f, ST[0], sxv + sy[0]), 0.f)));
      float A1 = __builtin_amdgcn_rcpf(1.0f + __builtin_amdgcn_sqrtf(fmaxf(__builtin_fmaf(-2.f, ST[1], sxv + sy[1]), 0.f)));
      float A2 = __builtin_amdgcn_rcpf(1.0f + __builtin_amdgcn_sqrtf(fmaxf(__builtin_fmaf(-2.f, ST[2], sxv + sy[2]), 0.f)));
      float A3 = __builtin_amdgcn_rcpf(1.0f + __builtin_amdgcn_sqrtf(fmaxf(__builtin_fmaf(-2.f, ST[3], sxv + sy[3]), 0.f)));
      *(uint2*)(Pb1 + pwo) = make_uint2(cvtpk(A0, A1), cvtpk(A2, A3));

      __syncthreads();  // P1 complete block-wide; tile 2*pr+2 staged in buf0

      bf8_t pf = *(const bf8_t*)(Pb1 + pro);
      acc[0] = __builtin_amdgcn_mfma_f32_16x16x32_bf16(pf, wf0, acc[0], 0, 0, 0);
      acc[1] = __builtin_amdgcn_mfma_f32_16x16x32_bf16(pf, wf1, acc[1], 0, 0, 0);
      acc[2] = __builtin_amdgcn_mfma_f32_16x16x32_bf16(pf, wf2, acc[2], 0, 0, 0);
      acc[3] = __builtin_amdgcn_mfma_f32_16x16x32_bf16(pf, wf3, acc[3], 0, 0, 0);
    }
  }

  // epilogue: direct store (wc owns d-half D0..D0+63; full K accumulated)
#pragma unroll
  for (int m = 0; m < 4; ++m) {
    const int d = D0 + m * 16 + l15;
#pragma unroll
    for (int r = 0; r < 4; ++r)
      Oc1[(size_t)(i0 + I0 + q * 4 + r) * D_ + d] = acc[m][r];
  }
}

extern "C" void kernel_launch(void* const* d_in, const int* in_sizes, int n_in,
                              void* d_out, int out_size, void* d_ws, size_t ws_size,
                              hipStream_t stream) {
  const float* x0 = (const float*)d_in[0];
  const float* x1 = (const float*)d_in[1];
  const float* W0 = (const float*)d_in[2];
  const float* W1 = (const float*)d_in[3];
  float* out = (float*)d_out;

  char* ws = (char*)d_ws;
  short* Wt = (short*)ws;                       // 512 KB, fragment-coalesced layout
  short* Xs = (short*)(ws + 524288);            // 16.78 MB, pre-swizzled bf16
  float* sq = (float*)(ws + 524288 + 16777216); // 256 KB

  prep_kernel<<<9216, 256, 0, stream>>>(x0, x1, W0, W1, Xs, sq, Wt, out);
  fused_attnconv<<<1024, NT, 0, stream>>>(Xs, sq, Wt, out);
}